// Round 7
// baseline (130.364 us; speedup 1.0000x reference)
//
#include <hip/hip_runtime.h>
#include <stdint.h>

typedef __attribute__((ext_vector_type(8))) short bf16x8;
typedef __attribute__((ext_vector_type(4))) float f32x4;

static constexpr int O1_ELEMS   = 512*3*3*128*128;    // 75497472 floats
static constexpr int WB2_FLOATS = 1048576;            // 4 MB bf16 wb2[a][k][b]
static constexpr int NTILES     = 4608;               // 512*9 tiles of 128x128 f32
static constexpr int HEAD_TILES = 64;                 // 64*64KB = 4MB = wb2 scratch
static constexpr int NCOMP      = 96;                 // 48 mt x 2 kt
static constexpr int NSTREAM    = 2272;               // (4608-64)/2272 = 2 tiles/blk

__device__ inline unsigned short f32_to_bf16(float f) {
    union { float f; uint32_t u; } v; v.f = f;
    uint32_t r = v.u + 0x7FFF + ((v.u >> 16) & 1);    // RNE
    return (unsigned short)(r >> 16);
}

__device__ inline bf16x8 bf16x8_from_f32(const float* p) {
    float4 v0 = *(const float4*)p;
    float4 v1 = *(const float4*)(p + 4);
    union { bf16x8 v; unsigned short s[8]; } u;
    u.s[0] = f32_to_bf16(v0.x); u.s[1] = f32_to_bf16(v0.y);
    u.s[2] = f32_to_bf16(v0.z); u.s[3] = f32_to_bf16(v0.w);
    u.s[4] = f32_to_bf16(v1.x); u.s[5] = f32_to_bf16(v1.y);
    u.s[6] = f32_to_bf16(v1.z); u.s[7] = f32_to_bf16(v1.w);
    return u.v;
}

// write one 128x128 out1 tile: out1[tile] = x[n,i,:] (rows) ⊗ y[n,j,:] (cols)
__device__ inline void write_tile(int tile, const float* __restrict__ x,
                                  const f32x4* __restrict__ y4,
                                  f32x4* __restrict__ o4, int t) {
    const int b4 = t & 31, a0 = t >> 5;               // b4: f4 col, a0: row group
    int n  = tile / 9;
    int ij = tile - n * 9;
    int i  = ij / 3, j = ij - i * 3;
    f32x4 yv = y4[(n * 3 + j) * 32 + b4];             // held in reg for 16 passes
    const float* xrow = x + (n * 3 + i) * 128;
    f32x4* dst = o4 + (size_t)tile * 4096 + a0 * 32 + b4;
    #pragma unroll
    for (int p = 0; p < 16; ++p) {
        float xs = xrow[p * 8 + a0];                  // 2-address wave broadcast
        f32x4 r = yv * xs;
        __builtin_nontemporal_store(r, dst);          // no L2 write-allocate
        dst += 256;                                   // 8 rows * 32 f4
    }
}

// ---- conv: wb2[a][k][b] = bf16(w[a][b][k]) (wb2 lives at out1 head) ----
__global__ __launch_bounds__(256) void conv_kernel(const float* __restrict__ w,
                                                   unsigned short* __restrict__ wb2) {
    __shared__ unsigned short lt[128][132];
    const int a = blockIdx.x;
    const int t = threadIdx.x;
    const float4* src = (const float4*)(w + (size_t)a * 16384);
    #pragma unroll
    for (int it = 0; it < 16; ++it) {                  // 4096 float4 = 128x128 f32
        int fidx = it * 256 + t;
        float4 v = src[fidx];
        int b = fidx >> 5, k4 = fidx & 31;
        unsigned short* d = &lt[b][k4 * 4];
        d[0] = f32_to_bf16(v.x); d[1] = f32_to_bf16(v.y);
        d[2] = f32_to_bf16(v.z); d[3] = f32_to_bf16(v.w);
    }
    __syncthreads();
    const int k = t >> 1, bh = t & 1;
    uint4* dst = (uint4*)(wb2 + (size_t)a * 16384 + (size_t)k * 128 + bh * 64);
    #pragma unroll
    for (int i8 = 0; i8 < 8; ++i8) {
        uint32_t pk[4];
        #pragma unroll
        for (int q = 0; q < 4; ++q) {
            uint32_t lo = lt[bh * 64 + i8 * 8 + q * 2][k];
            uint32_t hi = lt[bh * 64 + i8 * 8 + q * 2 + 1][k];
            pk[q] = lo | (hi << 16);
        }
        uint4 vv = {pk[0], pk[1], pk[2], pk[3]};
        dst[i8] = vv;
    }
}

// ---- mega: [0,NCOMP) fused out2 (all 128 a); [NCOMP,..) stream out1 tiles ----
__global__ __launch_bounds__(256) void mega_kernel(const float* __restrict__ x,
                                                   const float* __restrict__ y,
                                                   const float* __restrict__ a_s,
                                                   const unsigned short* __restrict__ wb2,
                                                   float* __restrict__ out1,
                                                   float* __restrict__ out2) {
    if ((int)blockIdx.x >= NCOMP) {
        const int sb = (int)blockIdx.x - NCOMP;
        const f32x4* y4 = (const f32x4*)y;
        f32x4* o4 = (f32x4*)out1;
        for (int tile = HEAD_TILES + sb; tile < NTILES; tile += NSTREAM)
            write_tile(tile, x, y4, o4, (int)threadIdx.x);
        return;
    }

    // compute block: out2 tile [mt*32..+32)m x [kt*64..+64)k, all a
    __shared__ float xsh[32][3][32];       // [ac][i][m']  12 KB, per 32-a chunk
    const int bid  = blockIdx.x;
    const int kt   = bid & 1;
    const int mt   = bid >> 1;             // 0..47
    const int tid  = threadIdx.x;
    const int l    = tid & 63;
    const int wv   = tid >> 6;             // wave -> k-cols [wv*16, +16)
    const int l15  = l & 15, lg = l >> 4;

    // A-frags (Y, bf16 cvt in-reg): row m = mt*32+Mt*16+l15, elems b = ks*32+lg*8..
    bf16x8 afrag[2][4];
    #pragma unroll
    for (int Mt = 0; Mt < 2; ++Mt)
        #pragma unroll
        for (int ks = 0; ks < 4; ++ks)
            afrag[Mt][ks] = bf16x8_from_f32(
                y + (size_t)(mt * 32 + Mt * 16 + l15) * 128 + ks * 32 + lg * 8);

    float acc2[3][2][4] = {};
    const unsigned short* wbase =
        wb2 + (size_t)(kt * 64 + wv * 16 + l15) * 128 + lg * 8;

    for (int seg = 0; seg < 4; ++seg) {
        __syncthreads();
        // x tile for this 32-a chunk: 32a x 3i x 32m = 3072 floats
        #pragma unroll
        for (int p = 0; p < 12; ++p) {
            int e = tid + p * 256;
            int ac = e / 96, r = e - ac * 96, i = r >> 5, mm = r & 31;
            int n = (mt * 32 + mm) / 3;
            xsh[ac][i][mm] = x[n * 384 + i * 128 + seg * 32 + ac];
        }
        __syncthreads();

        #pragma unroll 2
        for (int ac = 0; ac < 32; ++ac) {
            const int a = seg * 32 + ac;
            const unsigned short* wp = wbase + (size_t)a * 16384;
            bf16x8 bf0 = *(const bf16x8*)(wp);
            bf16x8 bf1 = *(const bf16x8*)(wp + 32);
            bf16x8 bf2 = *(const bf16x8*)(wp + 64);
            bf16x8 bf3 = *(const bf16x8*)(wp + 96);

            f32x4 t0 = {0.f, 0.f, 0.f, 0.f}, t1 = {0.f, 0.f, 0.f, 0.f};
            t0 = __builtin_amdgcn_mfma_f32_16x16x32_bf16(afrag[0][0], bf0, t0, 0, 0, 0);
            t1 = __builtin_amdgcn_mfma_f32_16x16x32_bf16(afrag[1][0], bf0, t1, 0, 0, 0);
            t0 = __builtin_amdgcn_mfma_f32_16x16x32_bf16(afrag[0][1], bf1, t0, 0, 0, 0);
            t1 = __builtin_amdgcn_mfma_f32_16x16x32_bf16(afrag[1][1], bf1, t1, 0, 0, 0);
            t0 = __builtin_amdgcn_mfma_f32_16x16x32_bf16(afrag[0][2], bf2, t0, 0, 0, 0);
            t1 = __builtin_amdgcn_mfma_f32_16x16x32_bf16(afrag[1][2], bf2, t1, 0, 0, 0);
            t0 = __builtin_amdgcn_mfma_f32_16x16x32_bf16(afrag[0][3], bf3, t0, 0, 0, 0);
            t1 = __builtin_amdgcn_mfma_f32_16x16x32_bf16(afrag[1][3], bf3, t1, 0, 0, 0);

            #pragma unroll
            for (int i = 0; i < 3; ++i) {
                float4 xv0 = *(const float4*)&xsh[ac][i][lg * 4];
                float4 xv1 = *(const float4*)&xsh[ac][i][16 + lg * 4];
                acc2[i][0][0] += xv0.x * t0[0]; acc2[i][0][1] += xv0.y * t0[1];
                acc2[i][0][2] += xv0.z * t0[2]; acc2[i][0][3] += xv0.w * t0[3];
                acc2[i][1][0] += xv1.x * t1[0]; acc2[i][1][1] += xv1.y * t1[1];
                acc2[i][1][2] += xv1.z * t1[2]; acc2[i][1][3] += xv1.w * t1[3];
            }
        }
    }

    const float alpha = 0.75f * a_s[0];
    const int kcol = kt * 64 + wv * 16 + l15;
    #pragma unroll
    for (int i = 0; i < 3; ++i)
        #pragma unroll
        for (int Mt = 0; Mt < 2; ++Mt)
            #pragma unroll
            for (int r = 0; r < 4; ++r) {
                int m = mt * 32 + Mt * 16 + lg * 4 + r;
                int n = m / 3, j = m - 3 * n;
                out2[((size_t)(n * 3 + i) * 3 + j) * 128 + kcol] = alpha * acc2[i][Mt][r];
            }
}

// ---- finish: rewrite out1 head (the wb2 scratch region = tiles 0..63) ----
__global__ __launch_bounds__(256) void finish_kernel(const float* __restrict__ x,
                                                     const float* __restrict__ y,
                                                     float* __restrict__ out1) {
    write_tile((int)blockIdx.x, x, (const f32x4*)y, (f32x4*)out1, (int)threadIdx.x);
}

extern "C" void kernel_launch(void* const* d_in, const int* in_sizes, int n_in,
                              void* d_out, int out_size, void* d_ws, size_t ws_size,
                              hipStream_t stream) {
    const float* w  = (const float*)d_in[0];
    const float* as = (const float*)d_in[1];
    const float* x  = (const float*)d_in[2];
    const float* y  = (const float*)d_in[3];
    float* out1 = (float*)d_out;
    float* out2 = out1 + O1_ELEMS;

    // wb2 scratch at out1 head (rewritten by finish): no ws dependency
    unsigned short* wb2 = (unsigned short*)out1;

    conv_kernel<<<128, 256, 0, stream>>>(w, wb2);
    mega_kernel<<<NCOMP + NSTREAM, 256, 0, stream>>>(x, y, as, wb2, out1, out2);
    finish_kernel<<<HEAD_TILES, 256, 0, stream>>>(x, y, out1);
}